// Round 3
// baseline (461.758 us; speedup 1.0000x reference)
//
#include <hip/hip_runtime.h>

#define IMG 28
#define NPIX (IMG * IMG)          // 784
#define NVEC (NPIX / 4)           // 196 float4 per image
#define CENTER 14

typedef float f32x4 __attribute__((ext_vector_type(4)));

// out = x everywhere except the annulus {(t-1)^2 < d2 <= t^2} (t=0: center
// pixel only), where out = x + conv3x3(x) + b (cross-correlation, SAME pad).
//
// Pure streaming design: one float4 per thread, no LDS, no __syncthreads.
// Conv neighbor taps (only on ~8% of pixels) read directly from global and
// hit L1/L2 (the lines were just streamed in). Nontemporal store for out
// (never re-read) keeps L2 for x.
__global__ __launch_bounds__(256) void SuperResolution_89876485636254_kernel(
    const float* __restrict__ x,
    const int*   __restrict__ t,
    const float* __restrict__ Wk,
    const float* __restrict__ bias,
    float*       __restrict__ out)
{
    const int k   = blockIdx.x * 256 + threadIdx.x;   // global float4 index
    const int img = k / NVEC;
    const int rem = k - img * NVEC;
    const int p   = rem * 4;                          // first pixel index
    const int i   = p / IMG;                          // row (4 pixels share it)
    const int j0  = p - i * IMG;

    const f32x4 v = ((const f32x4*)x)[k];
    float r[4] = {v.x, v.y, v.z, v.w};

    const int rt  = t[img];
    const int r2  = rt * rt;
    const int r12 = (rt - 1) * (rt - 1);              // only used when rt >= 1

    const int di  = i - CENTER;
    const int di2 = di * di;

    int  d2e[4];
    bool ann[4];
    bool any = false;
    #pragma unroll
    for (int e = 0; e < 4; ++e) {
        const int dj = j0 + e - CENTER;
        d2e[e] = di2 + dj * dj;
        ann[e] = (d2e[e] <= r2) && !((rt >= 1) && (d2e[e] <= r12));
        any = any || ann[e];
    }

    if (any) {
        float w[9];
        #pragma unroll
        for (int q = 0; q < 9; ++q) w[q] = Wk[q];
        const float bb = bias[0];
        const float* __restrict__ ximg = x + (size_t)img * NPIX;

        #pragma unroll
        for (int e = 0; e < 4; ++e) {
            if (ann[e]) {
                const int j = j0 + e;
                float acc = bb;
                #pragma unroll
                for (int a = 0; a < 3; ++a) {
                    const int ii = i + a - 1;
                    if (ii >= 0 && ii < IMG) {
                        #pragma unroll
                        for (int c = 0; c < 3; ++c) {
                            const int jj = j + c - 1;
                            if (jj >= 0 && jj < IMG)
                                acc += w[a * 3 + c] * ximg[ii * IMG + jj];
                        }
                    }
                }
                r[e] += acc;
            }
        }
    }

    f32x4 ov;
    ov.x = r[0]; ov.y = r[1]; ov.z = r[2]; ov.w = r[3];
    __builtin_nontemporal_store(ov, (f32x4*)out + k);
}

extern "C" void kernel_launch(void* const* d_in, const int* in_sizes, int n_in,
                              void* d_out, int out_size, void* d_ws, size_t ws_size,
                              hipStream_t stream) {
    const float* x    = (const float*)d_in[0];
    const int*   t    = (const int*)d_in[1];
    const float* Wk   = (const float*)d_in[2];
    const float* bias = (const float*)d_in[3];
    float*       out  = (float*)d_out;

    const int B      = in_sizes[0] / NPIX;            // 65536
    const int nvec   = B * NVEC;                      // total float4 elements
    const int blocks = (nvec + 255) / 256;            // 50176, exact

    SuperResolution_89876485636254_kernel<<<blocks, 256, 0, stream>>>(
        x, t, Wk, bias, out);
}